// Round 1
// baseline (2651.937 us; speedup 1.0000x reference)
//
#include <hip/hip_runtime.h>

#define NTOK 8192

// ---------------- patchify: x[B,3,256,256] -> flat[T,768] (C,P,P-major) -----
__global__ __launch_bounds__(256) void patch_kernel(const float* __restrict__ x,
                                                    float* __restrict__ flat)
{
  int t = blockIdx.x;          // 0..8191
  int tid = threadIdx.x;
  int b = t >> 8, ph = (t >> 4) & 15, pw = t & 15;
  const float* xb = x + (size_t)b * 3 * 256 * 256;
  #pragma unroll
  for (int r = 0; r < 3; ++r) {
    int d = r * 256 + tid;
    int c = d >> 8, i = (d >> 4) & 15, j = d & 15;
    flat[(size_t)t * 768 + d] = xb[((size_t)c * 256 + ph * 16 + i) * 256 + pw * 16 + j];
  }
}

// ---------------- gate: logits, top2 softmax, aux-loss accumulators --------
__global__ __launch_bounds__(256) void gate_kernel(const float* __restrict__ flat,
                                                   const float* __restrict__ gw,
                                                   const float* __restrict__ gb,
                                                   int* __restrict__ gidx,
                                                   float* __restrict__ gval,
                                                   float* __restrict__ aux)
{
  int wid = threadIdx.x >> 6, lane = threadIdx.x & 63;
  int t = blockIdx.x * 4 + wid;
  float acc[8];
  #pragma unroll
  for (int e = 0; e < 8; ++e) acc[e] = 0.f;
  const float* fr = flat + (size_t)t * 768;
  for (int k = lane; k < 768; k += 64) {
    float v = fr[k];
    const float* g = gw + k * 8;
    #pragma unroll
    for (int e = 0; e < 8; ++e) acc[e] += v * g[e];
  }
  #pragma unroll
  for (int e = 0; e < 8; ++e) {
    #pragma unroll
    for (int off = 32; off > 0; off >>= 1)
      acc[e] += __shfl_down(acc[e], off, 64);
  }
  if (lane == 0) {
    float lg[8];
    #pragma unroll
    for (int e = 0; e < 8; ++e) lg[e] = acc[e] + gb[e];
    int i0 = 0; float v0 = lg[0];
    #pragma unroll
    for (int e = 1; e < 8; ++e) if (lg[e] > v0) { v0 = lg[e]; i0 = e; }
    int i1 = -1; float v1 = -1e30f;
    #pragma unroll
    for (int e = 0; e < 8; ++e) { if (e == i0) continue; if (lg[e] > v1) { v1 = lg[e]; i1 = e; } }
    float e1 = __expf(v1 - v0);
    float s0 = 1.f / (1.f + e1);
    float s1 = e1 * s0;
    gidx[t * 2] = i0; gidx[t * 2 + 1] = i1;
    gval[t * 2] = s0; gval[t * 2 + 1] = s1;
    // full softmax for l_aux
    float sum = 0.f, p[8];
    #pragma unroll
    for (int e = 0; e < 8; ++e) { p[e] = __expf(lg[e] - v0); sum += p[e]; }
    float inv = 1.f / sum;
    #pragma unroll
    for (int e = 0; e < 8; ++e) atomicAdd(&aux[8 + e], p[e] * inv);
    atomicAdd(&aux[i0], 1.f);
  }
}

// ---------------- bin token-slots by expert --------------------------------
__global__ __launch_bounds__(256) void bin_kernel(const int* __restrict__ gidx,
                                                  int* __restrict__ cnt,
                                                  int* __restrict__ bin)
{
  int idx = blockIdx.x * 256 + threadIdx.x;   // 0..16383 (t*2+slot)
  int e = gidx[idx];
  int pos = atomicAdd(&cnt[e], 1);
  bin[e * 8192 + pos] = idx;
}

// ---------------- l_aux finalize -------------------------------------------
__global__ void laux_kernel(const float* __restrict__ aux, float* __restrict__ out)
{
  if (threadIdx.x == 0 && blockIdx.x == 0) {
    float l = 0.f;
    for (int e = 0; e < 8; ++e)
      l += (aux[e] / 8192.f) * (aux[8 + e] / 8192.f);
    out[2097152] = 8.f * l;
  }
}

// ---------------- expert CNN tower: one block per (token,slot) -------------
__global__ __launch_bounds__(256) void cnn_kernel(
    const float* __restrict__ flat, const int* __restrict__ gidx,
    const float* __restrict__ dw1w, const float* __restrict__ dw1b,
    const float* __restrict__ pw1w, const float* __restrict__ pw1b,
    const float* __restrict__ dw2w, const float* __restrict__ dw2b,
    const float* __restrict__ pw2w, const float* __restrict__ pw2b,
    const float* __restrict__ dw3w, const float* __restrict__ dw3b,
    const float* __restrict__ pw3w, const float* __restrict__ pw3b,
    float* __restrict__ feats)
{
  int ent = blockIdx.x;        // t*2+slot, 0..16383
  int t = ent >> 1;
  int e = gidx[ent];
  int tid = threadIdx.x;
  __shared__ float s_in[768];   // [3][16][16]
  __shared__ float s_a[192];    // dw1 out [3][8][8]
  __shared__ float s_b[4096];   // pw1 out [64][64]  (o*64 + p)
  __shared__ float s_c[1024];   // dw2 out [64][16]
  __shared__ float s_d[2048];   // pw2 out [128][16]
  __shared__ float s_e2[512];   // dw3 out [128][4]

  #pragma unroll
  for (int r = 0; r < 3; ++r) s_in[r * 256 + tid] = flat[(size_t)t * 768 + r * 256 + tid];
  __syncthreads();

  // dw1: depthwise 3x3 s2 p1, 16->8, C=3
  if (tid < 192) {
    int c = tid >> 6, p = tid & 63, oy = p >> 3, ox = p & 7;
    const float* w = dw1w + (e * 3 + c) * 9;
    float acc = dw1b[e * 3 + c];
    #pragma unroll
    for (int ky = 0; ky < 3; ++ky) {
      int iy = oy * 2 - 1 + ky; if ((unsigned)iy > 15u) continue;
      #pragma unroll
      for (int kx = 0; kx < 3; ++kx) {
        int ix = ox * 2 - 1 + kx; if ((unsigned)ix > 15u) continue;
        acc += w[ky * 3 + kx] * s_in[c * 256 + iy * 16 + ix];
      }
    }
    s_a[tid] = fmaxf(acc, 0.f);
  }
  __syncthreads();

  // pw1: 3 -> 64 over 64 positions
  #pragma unroll
  for (int r = 0; r < 16; ++r) {
    int idx = r * 256 + tid;
    int o = idx >> 6, p = idx & 63;
    const float* w = pw1w + (e * 64 + o) * 3;
    float v = pw1b[e * 64 + o] + w[0] * s_a[p] + w[1] * s_a[64 + p] + w[2] * s_a[128 + p];
    s_b[idx] = fmaxf(v, 0.f);
  }
  __syncthreads();

  // dw2: depthwise 3x3 s2 p1, 8->4, C=64
  #pragma unroll
  for (int r = 0; r < 4; ++r) {
    int idx = r * 256 + tid;
    int c = idx >> 4, p = idx & 15, oy = p >> 2, ox = p & 3;
    const float* w = dw2w + (e * 64 + c) * 9;
    float acc = dw2b[e * 64 + c];
    #pragma unroll
    for (int ky = 0; ky < 3; ++ky) {
      int iy = oy * 2 - 1 + ky; if ((unsigned)iy > 7u) continue;
      #pragma unroll
      for (int kx = 0; kx < 3; ++kx) {
        int ix = ox * 2 - 1 + kx; if ((unsigned)ix > 7u) continue;
        acc += w[ky * 3 + kx] * s_b[c * 64 + iy * 8 + ix];
      }
    }
    s_c[idx] = fmaxf(acc, 0.f);
  }
  __syncthreads();

  // pw2: 64 -> 128 over 16 positions
  #pragma unroll
  for (int r = 0; r < 8; ++r) {
    int idx = r * 256 + tid;
    int o = idx >> 4, p = idx & 15;
    const float* w = pw2w + (e * 128 + o) * 64;
    float acc = pw2b[e * 128 + o];
    #pragma unroll 16
    for (int c = 0; c < 64; ++c) acc += w[c] * s_c[c * 16 + p];
    s_d[idx] = fmaxf(acc, 0.f);
  }
  __syncthreads();

  // dw3: depthwise 3x3 s2 p1, 4->2, C=128
  #pragma unroll
  for (int r = 0; r < 2; ++r) {
    int idx = r * 256 + tid;
    int c = idx >> 2, p = idx & 3, oy = p >> 1, ox = p & 1;
    const float* w = dw3w + (e * 128 + c) * 9;
    float acc = dw3b[e * 128 + c];
    #pragma unroll
    for (int ky = 0; ky < 3; ++ky) {
      int iy = oy * 2 - 1 + ky; if ((unsigned)iy > 3u) continue;
      #pragma unroll
      for (int kx = 0; kx < 3; ++kx) {
        int ix = ox * 2 - 1 + kx; if ((unsigned)ix > 3u) continue;
        acc += w[ky * 3 + kx] * s_d[c * 16 + iy * 4 + ix];
      }
    }
    s_e2[idx] = fmaxf(acc, 0.f);
  }
  __syncthreads();

  // pw3: 128 -> 256 over 4 positions, relu, then mean-pool
  {
    int o = tid;
    const float* w = pw3w + (e * 256 + o) * 128;
    float bb = pw3b[e * 256 + o];
    float a0 = bb, a1 = bb, a2 = bb, a3 = bb;
    #pragma unroll 8
    for (int c = 0; c < 128; ++c) {
      float wc = w[c];
      a0 += wc * s_e2[c * 4 + 0];
      a1 += wc * s_e2[c * 4 + 1];
      a2 += wc * s_e2[c * 4 + 2];
      a3 += wc * s_e2[c * 4 + 3];
    }
    float f = fmaxf(a0, 0.f) + fmaxf(a1, 0.f) + fmaxf(a2, 0.f) + fmaxf(a3, 0.f);
    feats[(size_t)ent * 256 + o] = f * 0.25f;
  }
}

// ---------------- grouped combine GEMM: moe += g*(feats@th^T + flat@res^T + b)
__global__ __launch_bounds__(256) void combine_kernel(
    const float* __restrict__ flat, const float* __restrict__ feats,
    const float* __restrict__ gval, const int* __restrict__ bin,
    const int* __restrict__ cnt, const float* __restrict__ th_w,
    const float* __restrict__ th_b, const float* __restrict__ res_w,
    const float* __restrict__ res_b, float* __restrict__ moe)
{
  int e = blockIdx.z;
  int n = cnt[e];
  int chunk = blockIdx.x;
  if (chunk * 32 >= n) return;
  int dt = blockIdx.y;
  int tid = threadIdx.x;
  __shared__ int s_ent[32];
  __shared__ int s_tok[32];
  __shared__ float s_g[32];
  __shared__ float s_a[32 * 68];
  if (tid < 32) {
    int idx = chunk * 32 + tid;
    if (idx < n) {
      int ent = bin[e * 8192 + idx];
      s_ent[tid] = ent; s_tok[tid] = ent >> 1; s_g[tid] = gval[ent];
    } else { s_ent[tid] = 0; s_tok[tid] = 0; s_g[tid] = 0.f; }
  }
  __syncthreads();
  int d = dt * 256 + tid;
  float acc[32];
  #pragma unroll
  for (int s = 0; s < 32; ++s) acc[s] = 0.f;

  // phase 1: residual path, K=768, A = flat rows
  const float* wrow = res_w + ((size_t)e * 768 + d) * 768;
  for (int kb = 0; kb < 768; kb += 64) {
    #pragma unroll
    for (int r = 0; r < 8; ++r) {
      int li = r * 256 + tid;
      int s = li >> 6, k = li & 63;
      s_a[s * 68 + k] = flat[(size_t)s_tok[s] * 768 + kb + k];
    }
    __syncthreads();
    for (int k = 0; k < 64; k += 4) {
      float4 w4 = *reinterpret_cast<const float4*>(wrow + kb + k);
      #pragma unroll
      for (int s = 0; s < 32; ++s) {
        float4 a4 = *reinterpret_cast<const float4*>(&s_a[s * 68 + k]);
        acc[s] += w4.x * a4.x + w4.y * a4.y + w4.z * a4.z + w4.w * a4.w;
      }
    }
    __syncthreads();
  }

  // phase 2: to_hidden path, K=256, A = feats rows (per slot-entry)
  const float* wrow2 = th_w + ((size_t)e * 768 + d) * 256;
  for (int kb = 0; kb < 256; kb += 64) {
    #pragma unroll
    for (int r = 0; r < 8; ++r) {
      int li = r * 256 + tid;
      int s = li >> 6, k = li & 63;
      s_a[s * 68 + k] = feats[(size_t)s_ent[s] * 256 + kb + k];
    }
    __syncthreads();
    for (int k = 0; k < 64; k += 4) {
      float4 w4 = *reinterpret_cast<const float4*>(wrow2 + kb + k);
      #pragma unroll
      for (int s = 0; s < 32; ++s) {
        float4 a4 = *reinterpret_cast<const float4*>(&s_a[s * 68 + k]);
        acc[s] += w4.x * a4.x + w4.y * a4.y + w4.z * a4.z + w4.w * a4.w;
      }
    }
    __syncthreads();
  }

  float bsum = th_b[e * 768 + d] + res_b[e * 768 + d];
  #pragma unroll
  for (int s = 0; s < 32; ++s) {
    float v = s_g[s] * (acc[s] + bsum);
    atomicAdd(&moe[(size_t)s_tok[s] * 768 + d], v);
  }
}

// ---------------- final projection + transpose write -----------------------
__global__ __launch_bounds__(256) void emb_kernel(const float* __restrict__ moe,
                                                  const float* __restrict__ te_w,
                                                  const float* __restrict__ te_b,
                                                  float* __restrict__ out)
{
  int tt = blockIdx.x;          // 32-token tile
  int tid = threadIdx.x;        // output channel o
  __shared__ float s_a[32 * 68];
  float acc[32];
  #pragma unroll
  for (int s = 0; s < 32; ++s) acc[s] = 0.f;
  const float* wrow = te_w + (size_t)tid * 768;
  for (int kb = 0; kb < 768; kb += 64) {
    #pragma unroll
    for (int r = 0; r < 8; ++r) {
      int li = r * 256 + tid;
      int s = li >> 6, k = li & 63;
      s_a[s * 68 + k] = moe[((size_t)tt * 32 + s) * 768 + kb + k];
    }
    __syncthreads();
    for (int k = 0; k < 64; k += 4) {
      float4 w4 = *reinterpret_cast<const float4*>(wrow + kb + k);
      #pragma unroll
      for (int s = 0; s < 32; ++s) {
        float4 a4 = *reinterpret_cast<const float4*>(&s_a[s * 68 + k]);
        acc[s] += w4.x * a4.x + w4.y * a4.y + w4.z * a4.z + w4.w * a4.w;
      }
    }
    __syncthreads();
  }
  float b = te_b[tid];
  #pragma unroll
  for (int s = 0; s < 32; ++s) {
    int t = tt * 32 + s;
    int bi = t >> 8, nn = t & 255;
    out[(((size_t)bi * 256 + tid) << 8) + nn] = acc[s] + b;
  }
}

extern "C" void kernel_launch(void* const* d_in, const int* in_sizes, int n_in,
                              void* d_out, int out_size, void* d_ws, size_t ws_size,
                              hipStream_t stream)
{
  (void)in_sizes; (void)n_in; (void)out_size; (void)ws_size;
  const float* x    = (const float*)d_in[0];
  const float* gw   = (const float*)d_in[1];
  const float* gb   = (const float*)d_in[2];
  const float* dw1w = (const float*)d_in[3];
  const float* dw1b = (const float*)d_in[4];
  const float* pw1w = (const float*)d_in[5];
  const float* pw1b = (const float*)d_in[6];
  const float* dw2w = (const float*)d_in[7];
  const float* dw2b = (const float*)d_in[8];
  const float* pw2w = (const float*)d_in[9];
  const float* pw2b = (const float*)d_in[10];
  const float* dw3w = (const float*)d_in[11];
  const float* dw3b = (const float*)d_in[12];
  const float* pw3w = (const float*)d_in[13];
  const float* pw3b = (const float*)d_in[14];
  const float* thw  = (const float*)d_in[15];
  const float* thb  = (const float*)d_in[16];
  const float* resw = (const float*)d_in[17];
  const float* resb = (const float*)d_in[18];
  const float* tew  = (const float*)d_in[19];
  const float* teb  = (const float*)d_in[20];

  float* ws    = (float*)d_ws;
  float* flat  = ws;                      // 6291456 f
  float* moe   = ws + 6291456;            // 6291456 f
  float* feats = ws + 12582912;           // 4194304 f (ent*256)
  float* gval  = ws + 16777216;           // 16384 f
  int*   gidx  = (int*)(ws + 16793600);   // 16384 i
  float* aux   = ws + 16809984;           // 16 f (ce[8], me[8])
  int*   cnt   = (int*)(ws + 16810000);   // 8 i
  int*   bin   = (int*)(ws + 16810008);   // 65536 i
  float* out   = (float*)d_out;

  hipMemsetAsync(moe, 0, 6291456 * sizeof(float), stream);
  hipMemsetAsync(aux, 0, 24 * sizeof(float), stream);   // aux(16) + cnt(8)

  patch_kernel<<<8192, 256, 0, stream>>>(x, flat);
  gate_kernel<<<2048, 256, 0, stream>>>(flat, gw, gb, gidx, gval, aux);
  bin_kernel<<<64, 256, 0, stream>>>(gidx, cnt, bin);
  laux_kernel<<<1, 64, 0, stream>>>(aux, out);
  cnn_kernel<<<16384, 256, 0, stream>>>(flat, gidx, dw1w, dw1b, pw1w, pw1b,
                                        dw2w, dw2b, pw2w, pw2b, dw3w, dw3b,
                                        pw3w, pw3b, feats);
  dim3 cg(256, 3, 8);
  combine_kernel<<<cg, 256, 0, stream>>>(flat, feats, gval, bin, cnt,
                                         thw, thb, resw, resb, moe);
  emb_kernel<<<256, 256, 0, stream>>>(moe, tew, teb, out);
}

// Round 2
// 1662.711 us; speedup vs baseline: 1.5949x; 1.5949x over previous
//
#include <hip/hip_runtime.h>

#define NTOK 8192
#define GTOK 32   // tokens per gate block

// ---------------- patchify: x[B,3,256,256] -> flat[T,768] (C,P,P-major) -----
__global__ __launch_bounds__(256) void patch_kernel(const float* __restrict__ x,
                                                    float* __restrict__ flat)
{
  int t = blockIdx.x;          // 0..8191
  int tid = threadIdx.x;
  int b = t >> 8, ph = (t >> 4) & 15, pw = t & 15;
  const float* xb = x + (size_t)b * 3 * 256 * 256;
  #pragma unroll
  for (int r = 0; r < 3; ++r) {
    int d = r * 256 + tid;
    int c = d >> 8, i = (d >> 4) & 15, j = d & 15;
    flat[(size_t)t * 768 + d] = xb[((size_t)c * 256 + ph * 16 + i) * 256 + pw * 16 + j];
  }
}

// ---------------- gate: logits, top2 softmax, aux-loss accumulators --------
// aux layout (padded to one cache line per counter):
//   ce[e] at aux[e*16], me[e] at aux[128 + e*16]   (256 floats total)
__global__ __launch_bounds__(256) void gate_kernel(const float* __restrict__ flat,
                                                   const float* __restrict__ gw,
                                                   const float* __restrict__ gb,
                                                   int* __restrict__ gidx,
                                                   float* __restrict__ gval,
                                                   float* __restrict__ aux)
{
  __shared__ float s_red[16];   // [0..7] ce partial, [8..15] me partial
  int tid = threadIdx.x;
  if (tid < 16) s_red[tid] = 0.f;
  __syncthreads();
  int wid = tid >> 6, lane = tid & 63;

  for (int it = 0; it < GTOK / 4; ++it) {
    int t = blockIdx.x * GTOK + it * 4 + wid;
    float acc[8];
    #pragma unroll
    for (int e = 0; e < 8; ++e) acc[e] = 0.f;
    const float* fr = flat + (size_t)t * 768;
    for (int k = lane; k < 768; k += 64) {
      float v = fr[k];
      const float* g = gw + k * 8;
      #pragma unroll
      for (int e = 0; e < 8; ++e) acc[e] += v * g[e];
    }
    #pragma unroll
    for (int e = 0; e < 8; ++e) {
      #pragma unroll
      for (int off = 32; off > 0; off >>= 1)
        acc[e] += __shfl_down(acc[e], off, 64);
    }
    if (lane == 0) {
      float lg[8];
      #pragma unroll
      for (int e = 0; e < 8; ++e) lg[e] = acc[e] + gb[e];
      int i0 = 0; float v0 = lg[0];
      #pragma unroll
      for (int e = 1; e < 8; ++e) if (lg[e] > v0) { v0 = lg[e]; i0 = e; }
      int i1 = -1; float v1 = -1e30f;
      #pragma unroll
      for (int e = 0; e < 8; ++e) { if (e == i0) continue; if (lg[e] > v1) { v1 = lg[e]; i1 = e; } }
      float e1 = __expf(v1 - v0);
      float s0 = 1.f / (1.f + e1);
      float s1 = e1 * s0;
      gidx[t * 2] = i0; gidx[t * 2 + 1] = i1;
      gval[t * 2] = s0; gval[t * 2 + 1] = s1;
      // full softmax for l_aux, accumulated in LDS
      float sum = 0.f, p[8];
      #pragma unroll
      for (int e = 0; e < 8; ++e) { p[e] = __expf(lg[e] - v0); sum += p[e]; }
      float inv = 1.f / sum;
      #pragma unroll
      for (int e = 0; e < 8; ++e) atomicAdd(&s_red[8 + e], p[e] * inv);
      atomicAdd(&s_red[i0], 1.f);
    }
  }
  __syncthreads();
  if (tid < 8) {
    atomicAdd(&aux[tid * 16], s_red[tid]);          // ce
    atomicAdd(&aux[128 + tid * 16], s_red[8 + tid]); // me
  }
}

// ---------------- bin token-slots by expert --------------------------------
__global__ __launch_bounds__(256) void bin_kernel(const int* __restrict__ gidx,
                                                  int* __restrict__ cnt,
                                                  int* __restrict__ bin)
{
  int idx = blockIdx.x * 256 + threadIdx.x;   // 0..16383 (t*2+slot)
  int e = gidx[idx];
  int pos = atomicAdd(&cnt[e], 1);
  bin[e * 8192 + pos] = idx;
}

// ---------------- l_aux finalize -------------------------------------------
__global__ void laux_kernel(const float* __restrict__ aux, float* __restrict__ out)
{
  if (threadIdx.x == 0 && blockIdx.x == 0) {
    float l = 0.f;
    for (int e = 0; e < 8; ++e)
      l += (aux[e * 16] / 8192.f) * (aux[128 + e * 16] / 8192.f);
    out[2097152] = 8.f * l;
  }
}

// ---------------- expert CNN tower: one block per (token,slot) -------------
__global__ __launch_bounds__(256) void cnn_kernel(
    const float* __restrict__ flat, const int* __restrict__ gidx,
    const float* __restrict__ dw1w, const float* __restrict__ dw1b,
    const float* __restrict__ pw1w, const float* __restrict__ pw1b,
    const float* __restrict__ dw2w, const float* __restrict__ dw2b,
    const float* __restrict__ pw2w, const float* __restrict__ pw2b,
    const float* __restrict__ dw3w, const float* __restrict__ dw3b,
    const float* __restrict__ pw3w, const float* __restrict__ pw3b,
    float* __restrict__ feats)
{
  int ent = blockIdx.x;        // t*2+slot, 0..16383
  int t = ent >> 1;
  int e = gidx[ent];
  int tid = threadIdx.x;
  __shared__ float s_in[768];   // [3][16][16]
  __shared__ float s_a[192];    // dw1 out [3][8][8]
  __shared__ float s_b[4096];   // pw1 out [64][64]  (o*64 + p)
  __shared__ float s_c[1024];   // dw2 out [64][16]
  __shared__ float s_d[2048];   // pw2 out [128][16]
  __shared__ float s_e2[512];   // dw3 out [128][4]

  #pragma unroll
  for (int r = 0; r < 3; ++r) s_in[r * 256 + tid] = flat[(size_t)t * 768 + r * 256 + tid];
  __syncthreads();

  // dw1: depthwise 3x3 s2 p1, 16->8, C=3
  if (tid < 192) {
    int c = tid >> 6, p = tid & 63, oy = p >> 3, ox = p & 7;
    const float* w = dw1w + (e * 3 + c) * 9;
    float acc = dw1b[e * 3 + c];
    #pragma unroll
    for (int ky = 0; ky < 3; ++ky) {
      int iy = oy * 2 - 1 + ky; if ((unsigned)iy > 15u) continue;
      #pragma unroll
      for (int kx = 0; kx < 3; ++kx) {
        int ix = ox * 2 - 1 + kx; if ((unsigned)ix > 15u) continue;
        acc += w[ky * 3 + kx] * s_in[c * 256 + iy * 16 + ix];
      }
    }
    s_a[tid] = fmaxf(acc, 0.f);
  }
  __syncthreads();

  // pw1: 3 -> 64 over 64 positions
  #pragma unroll
  for (int r = 0; r < 16; ++r) {
    int idx = r * 256 + tid;
    int o = idx >> 6, p = idx & 63;
    const float* w = pw1w + (e * 64 + o) * 3;
    float v = pw1b[e * 64 + o] + w[0] * s_a[p] + w[1] * s_a[64 + p] + w[2] * s_a[128 + p];
    s_b[idx] = fmaxf(v, 0.f);
  }
  __syncthreads();

  // dw2: depthwise 3x3 s2 p1, 8->4, C=64
  #pragma unroll
  for (int r = 0; r < 4; ++r) {
    int idx = r * 256 + tid;
    int c = idx >> 4, p = idx & 15, oy = p >> 2, ox = p & 3;
    const float* w = dw2w + (e * 64 + c) * 9;
    float acc = dw2b[e * 64 + c];
    #pragma unroll
    for (int ky = 0; ky < 3; ++ky) {
      int iy = oy * 2 - 1 + ky; if ((unsigned)iy > 7u) continue;
      #pragma unroll
      for (int kx = 0; kx < 3; ++kx) {
        int ix = ox * 2 - 1 + kx; if ((unsigned)ix > 7u) continue;
        acc += w[ky * 3 + kx] * s_b[c * 64 + iy * 8 + ix];
      }
    }
    s_c[idx] = fmaxf(acc, 0.f);
  }
  __syncthreads();

  // pw2: 64 -> 128 over 16 positions
  #pragma unroll
  for (int r = 0; r < 8; ++r) {
    int idx = r * 256 + tid;
    int o = idx >> 4, p = idx & 15;
    const float* w = pw2w + (e * 128 + o) * 64;
    float acc = pw2b[e * 128 + o];
    #pragma unroll 16
    for (int c = 0; c < 64; ++c) acc += w[c] * s_c[c * 16 + p];
    s_d[idx] = fmaxf(acc, 0.f);
  }
  __syncthreads();

  // dw3: depthwise 3x3 s2 p1, 4->2, C=128
  #pragma unroll
  for (int r = 0; r < 2; ++r) {
    int idx = r * 256 + tid;
    int c = idx >> 2, p = idx & 3, oy = p >> 1, ox = p & 1;
    const float* w = dw3w + (e * 128 + c) * 9;
    float acc = dw3b[e * 128 + c];
    #pragma unroll
    for (int ky = 0; ky < 3; ++ky) {
      int iy = oy * 2 - 1 + ky; if ((unsigned)iy > 3u) continue;
      #pragma unroll
      for (int kx = 0; kx < 3; ++kx) {
        int ix = ox * 2 - 1 + kx; if ((unsigned)ix > 3u) continue;
        acc += w[ky * 3 + kx] * s_d[c * 16 + iy * 4 + ix];
      }
    }
    s_e2[idx] = fmaxf(acc, 0.f);
  }
  __syncthreads();

  // pw3: 128 -> 256 over 4 positions, relu, then mean-pool
  {
    int o = tid;
    const float* w = pw3w + (e * 256 + o) * 128;
    float bb = pw3b[e * 256 + o];
    float a0 = bb, a1 = bb, a2 = bb, a3 = bb;
    #pragma unroll 8
    for (int c = 0; c < 128; ++c) {
      float wc = w[c];
      a0 += wc * s_e2[c * 4 + 0];
      a1 += wc * s_e2[c * 4 + 1];
      a2 += wc * s_e2[c * 4 + 2];
      a3 += wc * s_e2[c * 4 + 3];
    }
    float f = fmaxf(a0, 0.f) + fmaxf(a1, 0.f) + fmaxf(a2, 0.f) + fmaxf(a3, 0.f);
    feats[(size_t)ent * 256 + o] = f * 0.25f;
  }
}

// ---------------- grouped combine GEMM: moe += g*(feats@th^T + flat@res^T + b)
__global__ __launch_bounds__(256) void combine_kernel(
    const float* __restrict__ flat, const float* __restrict__ feats,
    const float* __restrict__ gval, const int* __restrict__ bin,
    const int* __restrict__ cnt, const float* __restrict__ th_w,
    const float* __restrict__ th_b, const float* __restrict__ res_w,
    const float* __restrict__ res_b, float* __restrict__ moe)
{
  int e = blockIdx.z;
  int n = cnt[e];
  int chunk = blockIdx.x;
  if (chunk * 32 >= n) return;
  int dt = blockIdx.y;
  int tid = threadIdx.x;
  __shared__ int s_ent[32];
  __shared__ int s_tok[32];
  __shared__ float s_g[32];
  __shared__ float s_a[32 * 68];
  if (tid < 32) {
    int idx = chunk * 32 + tid;
    if (idx < n) {
      int ent = bin[e * 8192 + idx];
      s_ent[tid] = ent; s_tok[tid] = ent >> 1; s_g[tid] = gval[ent];
    } else { s_ent[tid] = 0; s_tok[tid] = 0; s_g[tid] = 0.f; }
  }
  __syncthreads();
  int d = dt * 256 + tid;
  float acc[32];
  #pragma unroll
  for (int s = 0; s < 32; ++s) acc[s] = 0.f;

  // phase 1: residual path, K=768, A = flat rows
  const float* wrow = res_w + ((size_t)e * 768 + d) * 768;
  for (int kb = 0; kb < 768; kb += 64) {
    #pragma unroll
    for (int r = 0; r < 8; ++r) {
      int li = r * 256 + tid;
      int s = li >> 6, k = li & 63;
      s_a[s * 68 + k] = flat[(size_t)s_tok[s] * 768 + kb + k];
    }
    __syncthreads();
    for (int k = 0; k < 64; k += 4) {
      float4 w4 = *reinterpret_cast<const float4*>(wrow + kb + k);
      #pragma unroll
      for (int s = 0; s < 32; ++s) {
        float4 a4 = *reinterpret_cast<const float4*>(&s_a[s * 68 + k]);
        acc[s] += w4.x * a4.x + w4.y * a4.y + w4.z * a4.z + w4.w * a4.w;
      }
    }
    __syncthreads();
  }

  // phase 2: to_hidden path, K=256, A = feats rows (per slot-entry)
  const float* wrow2 = th_w + ((size_t)e * 768 + d) * 256;
  for (int kb = 0; kb < 256; kb += 64) {
    #pragma unroll
    for (int r = 0; r < 8; ++r) {
      int li = r * 256 + tid;
      int s = li >> 6, k = li & 63;
      s_a[s * 68 + k] = feats[(size_t)s_ent[s] * 256 + kb + k];
    }
    __syncthreads();
    for (int k = 0; k < 64; k += 4) {
      float4 w4 = *reinterpret_cast<const float4*>(wrow2 + kb + k);
      #pragma unroll
      for (int s = 0; s < 32; ++s) {
        float4 a4 = *reinterpret_cast<const float4*>(&s_a[s * 68 + k]);
        acc[s] += w4.x * a4.x + w4.y * a4.y + w4.z * a4.z + w4.w * a4.w;
      }
    }
    __syncthreads();
  }

  float bsum = th_b[e * 768 + d] + res_b[e * 768 + d];
  #pragma unroll
  for (int s = 0; s < 32; ++s) {
    float v = s_g[s] * (acc[s] + bsum);
    atomicAdd(&moe[(size_t)s_tok[s] * 768 + d], v);
  }
}

// ---------------- final projection + transpose write -----------------------
__global__ __launch_bounds__(256) void emb_kernel(const float* __restrict__ moe,
                                                  const float* __restrict__ te_w,
                                                  const float* __restrict__ te_b,
                                                  float* __restrict__ out)
{
  int tt = blockIdx.x;          // 32-token tile
  int tid = threadIdx.x;        // output channel o
  __shared__ float s_a[32 * 68];
  float acc[32];
  #pragma unroll
  for (int s = 0; s < 32; ++s) acc[s] = 0.f;
  const float* wrow = te_w + (size_t)tid * 768;
  for (int kb = 0; kb < 768; kb += 64) {
    #pragma unroll
    for (int r = 0; r < 8; ++r) {
      int li = r * 256 + tid;
      int s = li >> 6, k = li & 63;
      s_a[s * 68 + k] = moe[((size_t)tt * 32 + s) * 768 + kb + k];
    }
    __syncthreads();
    for (int k = 0; k < 64; k += 4) {
      float4 w4 = *reinterpret_cast<const float4*>(wrow + kb + k);
      #pragma unroll
      for (int s = 0; s < 32; ++s) {
        float4 a4 = *reinterpret_cast<const float4*>(&s_a[s * 68 + k]);
        acc[s] += w4.x * a4.x + w4.y * a4.y + w4.z * a4.z + w4.w * a4.w;
      }
    }
    __syncthreads();
  }
  float b = te_b[tid];
  #pragma unroll
  for (int s = 0; s < 32; ++s) {
    int t = tt * 32 + s;
    int bi = t >> 8, nn = t & 255;
    out[(((size_t)bi * 256 + tid) << 8) + nn] = acc[s] + b;
  }
}

extern "C" void kernel_launch(void* const* d_in, const int* in_sizes, int n_in,
                              void* d_out, int out_size, void* d_ws, size_t ws_size,
                              hipStream_t stream)
{
  (void)in_sizes; (void)n_in; (void)out_size; (void)ws_size;
  const float* x    = (const float*)d_in[0];
  const float* gw   = (const float*)d_in[1];
  const float* gb   = (const float*)d_in[2];
  const float* dw1w = (const float*)d_in[3];
  const float* dw1b = (const float*)d_in[4];
  const float* pw1w = (const float*)d_in[5];
  const float* pw1b = (const float*)d_in[6];
  const float* dw2w = (const float*)d_in[7];
  const float* dw2b = (const float*)d_in[8];
  const float* pw2w = (const float*)d_in[9];
  const float* pw2b = (const float*)d_in[10];
  const float* dw3w = (const float*)d_in[11];
  const float* dw3b = (const float*)d_in[12];
  const float* pw3w = (const float*)d_in[13];
  const float* pw3b = (const float*)d_in[14];
  const float* thw  = (const float*)d_in[15];
  const float* thb  = (const float*)d_in[16];
  const float* resw = (const float*)d_in[17];
  const float* resb = (const float*)d_in[18];
  const float* tew  = (const float*)d_in[19];
  const float* teb  = (const float*)d_in[20];

  float* ws    = (float*)d_ws;
  float* flat  = ws;                      // 6291456 f
  float* moe   = ws + 6291456;            // 6291456 f
  float* feats = ws + 12582912;           // 4194304 f (ent*256)
  float* gval  = ws + 16777216;           // 16384 f
  int*   gidx  = (int*)(ws + 16793600);   // 16384 i
  float* aux   = ws + 16809984;           // 256 f (ce[e] at e*16, me[e] at 128+e*16)
  int*   cnt   = (int*)(ws + 16810240);   // 8 i
  int*   bin   = (int*)(ws + 16810248);   // 65536 i
  float* out   = (float*)d_out;

  hipMemsetAsync(moe, 0, 6291456 * sizeof(float), stream);
  hipMemsetAsync(aux, 0, 264 * sizeof(float), stream);   // aux(256) + cnt(8)

  patch_kernel<<<8192, 256, 0, stream>>>(x, flat);
  gate_kernel<<<NTOK / GTOK, 256, 0, stream>>>(flat, gw, gb, gidx, gval, aux);
  bin_kernel<<<64, 256, 0, stream>>>(gidx, cnt, bin);
  laux_kernel<<<1, 64, 0, stream>>>(aux, out);
  cnn_kernel<<<16384, 256, 0, stream>>>(flat, gidx, dw1w, dw1b, pw1w, pw1b,
                                        dw2w, dw2b, pw2w, pw2b, dw3w, dw3b,
                                        pw3w, pw3b, feats);
  dim3 cg(256, 3, 8);
  combine_kernel<<<cg, 256, 0, stream>>>(flat, feats, gval, bin, cnt,
                                         thw, thb, resw, resb, moe);
  emb_kernel<<<256, 256, 0, stream>>>(moe, tew, teb, out);
}

// Round 3
// 919.961 us; speedup vs baseline: 2.8827x; 1.8074x over previous
//
#include <hip/hip_runtime.h>

#define NTOK 8192
#define GTOK 32   // tokens per gate block

typedef __attribute__((ext_vector_type(8))) short short8;
typedef __attribute__((ext_vector_type(4))) float f32x4;

__device__ __forceinline__ unsigned short f2bf(float f) {
  unsigned u = __float_as_uint(f);
  u += 0x7FFFu + ((u >> 16) & 1u);
  return (unsigned short)(u >> 16);
}

// ---------------- patchify: x[B,3,256,256] -> flat[T,768] (C,P,P-major) -----
__global__ __launch_bounds__(256) void patch_kernel(const float* __restrict__ x,
                                                    float* __restrict__ flat)
{
  int t = blockIdx.x;          // 0..8191
  int tid = threadIdx.x;
  int b = t >> 8, ph = (t >> 4) & 15, pw = t & 15;
  const float* xb = x + (size_t)b * 3 * 256 * 256;
  #pragma unroll
  for (int r = 0; r < 3; ++r) {
    int d = r * 256 + tid;
    int c = d >> 8, i = (d >> 4) & 15, j = d & 15;
    flat[(size_t)t * 768 + d] = xb[((size_t)c * 256 + ph * 16 + i) * 256 + pw * 16 + j];
  }
}

// ---------------- gate (fp32 flat; LDS-reduced aux) ------------------------
__global__ __launch_bounds__(256) void gate_kernel(const float* __restrict__ flat,
                                                   const float* __restrict__ gw,
                                                   const float* __restrict__ gb,
                                                   int* __restrict__ gidx,
                                                   float* __restrict__ gval,
                                                   float* __restrict__ aux)
{
  __shared__ float s_red[16];   // [0..7] ce partial, [8..15] me partial
  int tid = threadIdx.x;
  if (tid < 16) s_red[tid] = 0.f;
  __syncthreads();
  int wid = tid >> 6, lane = tid & 63;

  for (int it = 0; it < GTOK / 4; ++it) {
    int t = blockIdx.x * GTOK + it * 4 + wid;
    float acc[8];
    #pragma unroll
    for (int e = 0; e < 8; ++e) acc[e] = 0.f;
    const float* fr = flat + (size_t)t * 768;
    for (int k = lane; k < 768; k += 64) {
      float v = fr[k];
      const float* g = gw + k * 8;
      #pragma unroll
      for (int e = 0; e < 8; ++e) acc[e] += v * g[e];
    }
    #pragma unroll
    for (int e = 0; e < 8; ++e) {
      #pragma unroll
      for (int off = 32; off > 0; off >>= 1)
        acc[e] += __shfl_down(acc[e], off, 64);
    }
    if (lane == 0) {
      float lg[8];
      #pragma unroll
      for (int e = 0; e < 8; ++e) lg[e] = acc[e] + gb[e];
      int i0 = 0; float v0 = lg[0];
      #pragma unroll
      for (int e = 1; e < 8; ++e) if (lg[e] > v0) { v0 = lg[e]; i0 = e; }
      int i1 = -1; float v1 = -1e30f;
      #pragma unroll
      for (int e = 0; e < 8; ++e) { if (e == i0) continue; if (lg[e] > v1) { v1 = lg[e]; i1 = e; } }
      float e1 = __expf(v1 - v0);
      float s0 = 1.f / (1.f + e1);
      float s1 = e1 * s0;
      gidx[t * 2] = i0; gidx[t * 2 + 1] = i1;
      gval[t * 2] = s0; gval[t * 2 + 1] = s1;
      float sum = 0.f, p[8];
      #pragma unroll
      for (int e = 0; e < 8; ++e) { p[e] = __expf(lg[e] - v0); sum += p[e]; }
      float inv = 1.f / sum;
      #pragma unroll
      for (int e = 0; e < 8; ++e) atomicAdd(&s_red[8 + e], p[e] * inv);
      atomicAdd(&s_red[i0], 1.f);
    }
  }
  __syncthreads();
  if (tid < 8) {
    atomicAdd(&aux[tid * 16], s_red[tid]);           // ce
    atomicAdd(&aux[128 + tid * 16], s_red[8 + tid]); // me
  }
}

// ---------------- bin token-slots by expert --------------------------------
__global__ __launch_bounds__(256) void bin_kernel(const int* __restrict__ gidx,
                                                  int* __restrict__ cnt,
                                                  int* __restrict__ bin)
{
  int idx = blockIdx.x * 256 + threadIdx.x;   // 0..16383 (t*2+slot)
  int e = gidx[idx];
  int pos = atomicAdd(&cnt[e], 1);
  bin[e * 8192 + pos] = idx;
}

// ---------------- l_aux finalize -------------------------------------------
__global__ void laux_kernel(const float* __restrict__ aux, float* __restrict__ out)
{
  if (threadIdx.x == 0 && blockIdx.x == 0) {
    float l = 0.f;
    for (int e = 0; e < 8; ++e)
      l += (aux[e * 16] / 8192.f) * (aux[128 + e * 16] / 8192.f);
    out[2097152] = 8.f * l;
  }
}

// ---------------- fp32 -> bf16 bulk convert (n multiple of 1024) -----------
__global__ __launch_bounds__(256) void f2bf_kernel(const float* __restrict__ in,
                                                   unsigned short* __restrict__ out)
{
  size_t i = (size_t)blockIdx.x * 1024 + threadIdx.x * 4;
  float4 v = *reinterpret_cast<const float4*>(in + i);
  ushort4 o;
  o.x = f2bf(v.x); o.y = f2bf(v.y); o.z = f2bf(v.z); o.w = f2bf(v.w);
  *reinterpret_cast<ushort4*>(out + i) = o;
}

// ---------------- Wcat[e][o][1024] = res_w[e][o][0:768] || th_w[e][o][0:256]
__global__ __launch_bounds__(256) void wcat_kernel(const float* __restrict__ resw,
                                                   const float* __restrict__ thw,
                                                   unsigned short* __restrict__ Wcat)
{
  int row = blockIdx.x;               // 0..6143 == e*768+o
  int k = threadIdx.x * 4;            // 0..1023
  float4 v;
  if (k < 768) v = *reinterpret_cast<const float4*>(resw + (size_t)row * 768 + k);
  else         v = *reinterpret_cast<const float4*>(thw + (size_t)row * 256 + (k - 768));
  ushort4 o;
  o.x = f2bf(v.x); o.y = f2bf(v.y); o.z = f2bf(v.z); o.w = f2bf(v.w);
  *reinterpret_cast<ushort4*>(Wcat + (size_t)row * 1024 + k) = o;
}

// ---------------- expert CNN tower: one block per (token,slot) -------------
__global__ __launch_bounds__(256) void cnn_kernel(
    const float* __restrict__ flat, const int* __restrict__ gidx,
    const float* __restrict__ dw1w, const float* __restrict__ dw1b,
    const float* __restrict__ pw1w, const float* __restrict__ pw1b,
    const float* __restrict__ dw2w, const float* __restrict__ dw2b,
    const float* __restrict__ pw2w, const float* __restrict__ pw2b,
    const float* __restrict__ dw3w, const float* __restrict__ dw3b,
    const float* __restrict__ pw3w, const float* __restrict__ pw3b,
    float* __restrict__ feats)
{
  int ent = blockIdx.x;        // t*2+slot, 0..16383
  int t = ent >> 1;
  int e = gidx[ent];
  int tid = threadIdx.x;
  __shared__ float s_in[768];   // [3][16][16]
  __shared__ float s_a[192];    // dw1 out [3][8][8]
  __shared__ float s_b[4096];   // pw1 out [64][64]  (o*64 + p)
  __shared__ float s_c[1024];   // dw2 out [64][16]
  __shared__ float s_d[2048];   // pw2 out [128][16]
  __shared__ float s_e2[512];   // dw3 out [128][4]

  #pragma unroll
  for (int r = 0; r < 3; ++r) s_in[r * 256 + tid] = flat[(size_t)t * 768 + r * 256 + tid];
  __syncthreads();

  if (tid < 192) {
    int c = tid >> 6, p = tid & 63, oy = p >> 3, ox = p & 7;
    const float* w = dw1w + (e * 3 + c) * 9;
    float acc = dw1b[e * 3 + c];
    #pragma unroll
    for (int ky = 0; ky < 3; ++ky) {
      int iy = oy * 2 - 1 + ky; if ((unsigned)iy > 15u) continue;
      #pragma unroll
      for (int kx = 0; kx < 3; ++kx) {
        int ix = ox * 2 - 1 + kx; if ((unsigned)ix > 15u) continue;
        acc += w[ky * 3 + kx] * s_in[c * 256 + iy * 16 + ix];
      }
    }
    s_a[tid] = fmaxf(acc, 0.f);
  }
  __syncthreads();

  #pragma unroll
  for (int r = 0; r < 16; ++r) {
    int idx = r * 256 + tid;
    int o = idx >> 6, p = idx & 63;
    const float* w = pw1w + (e * 64 + o) * 3;
    float v = pw1b[e * 64 + o] + w[0] * s_a[p] + w[1] * s_a[64 + p] + w[2] * s_a[128 + p];
    s_b[idx] = fmaxf(v, 0.f);
  }
  __syncthreads();

  #pragma unroll
  for (int r = 0; r < 4; ++r) {
    int idx = r * 256 + tid;
    int c = idx >> 4, p = idx & 15, oy = p >> 2, ox = p & 3;
    const float* w = dw2w + (e * 64 + c) * 9;
    float acc = dw2b[e * 64 + c];
    #pragma unroll
    for (int ky = 0; ky < 3; ++ky) {
      int iy = oy * 2 - 1 + ky; if ((unsigned)iy > 7u) continue;
      #pragma unroll
      for (int kx = 0; kx < 3; ++kx) {
        int ix = ox * 2 - 1 + kx; if ((unsigned)ix > 7u) continue;
        acc += w[ky * 3 + kx] * s_b[c * 64 + iy * 8 + ix];
      }
    }
    s_c[idx] = fmaxf(acc, 0.f);
  }
  __syncthreads();

  #pragma unroll
  for (int r = 0; r < 8; ++r) {
    int idx = r * 256 + tid;
    int o = idx >> 4, p = idx & 15;
    const float* w = pw2w + (e * 128 + o) * 64;
    float acc = pw2b[e * 128 + o];
    #pragma unroll 16
    for (int c = 0; c < 64; ++c) acc += w[c] * s_c[c * 16 + p];
    s_d[idx] = fmaxf(acc, 0.f);
  }
  __syncthreads();

  #pragma unroll
  for (int r = 0; r < 2; ++r) {
    int idx = r * 256 + tid;
    int c = idx >> 2, p = idx & 3, oy = p >> 1, ox = p & 1;
    const float* w = dw3w + (e * 128 + c) * 9;
    float acc = dw3b[e * 128 + c];
    #pragma unroll
    for (int ky = 0; ky < 3; ++ky) {
      int iy = oy * 2 - 1 + ky; if ((unsigned)iy > 3u) continue;
      #pragma unroll
      for (int kx = 0; kx < 3; ++kx) {
        int ix = ox * 2 - 1 + kx; if ((unsigned)ix > 3u) continue;
        acc += w[ky * 3 + kx] * s_d[c * 16 + iy * 4 + ix];
      }
    }
    s_e2[idx] = fmaxf(acc, 0.f);
  }
  __syncthreads();

  {
    int o = tid;
    const float* w = pw3w + (e * 256 + o) * 128;
    float bb = pw3b[e * 256 + o];
    float a0 = bb, a1 = bb, a2 = bb, a3 = bb;
    #pragma unroll 8
    for (int c = 0; c < 128; ++c) {
      float wc = w[c];
      a0 += wc * s_e2[c * 4 + 0];
      a1 += wc * s_e2[c * 4 + 1];
      a2 += wc * s_e2[c * 4 + 2];
      a3 += wc * s_e2[c * 4 + 3];
    }
    float f = fmaxf(a0, 0.f) + fmaxf(a1, 0.f) + fmaxf(a2, 0.f) + fmaxf(a3, 0.f);
    feats[(size_t)ent * 256 + o] = f * 0.25f;
  }
}

// ---------------- grouped combine GEMM via MFMA ----------------------------
// C[entry, d] = flatbf[tok]·Wcat[e][d][0:768] + featsbf[ent]·Wcat[e][d][768:1024]
// moe[tok][d] += gate * (C + th_b + res_b)
__global__ __launch_bounds__(256) void combine_mfma(
    const unsigned short* __restrict__ flatbf,   // [8192][768]
    const unsigned short* __restrict__ featsbf,  // [16384][256]
    const unsigned short* __restrict__ Wcat,     // [8][768][1024]
    const float* __restrict__ gval, const int* __restrict__ bin,
    const int* __restrict__ cnt, const float* __restrict__ th_b,
    const float* __restrict__ res_b, float* __restrict__ moe)
{
  int e = blockIdx.z;
  int n = cnt[e];
  int chunk = blockIdx.x;
  if (chunk * 32 >= n) return;
  int dt = blockIdx.y;          // 0..2
  int tid = threadIdx.x;
  int wid = tid >> 6, lane = tid & 63;
  __shared__ int s_ent[32];
  __shared__ int s_tok[32];
  __shared__ float s_g[32];
  if (tid < 32) {
    int idx = chunk * 32 + tid;
    if (idx < n) {
      int ent = bin[e * 8192 + idx];
      s_ent[tid] = ent; s_tok[tid] = ent >> 1; s_g[tid] = gval[ent];
    } else {
      int ent0 = bin[e * 8192];
      s_ent[tid] = ent0; s_tok[tid] = ent0 >> 1; s_g[tid] = 0.f;
    }
  }
  __syncthreads();

  int lr = lane & 15, kg = lane >> 4;   // row/col-in-tile, k-group
  int n0 = dt * 256 + wid * 64;
  const unsigned short* a0f = flatbf + (size_t)s_tok[lr] * 768 + kg * 8;
  const unsigned short* a1f = flatbf + (size_t)s_tok[16 + lr] * 768 + kg * 8;
  const unsigned short* bp = Wcat + ((size_t)e * 768 + n0 + lr) * 1024 + kg * 8;

  f32x4 acc[2][4] = {};

  // K phase 1: residual path (flat · res_w^T), K=768
  for (int kb = 0; kb < 768; kb += 32) {
    short8 a0 = *reinterpret_cast<const short8*>(a0f + kb);
    short8 a1 = *reinterpret_cast<const short8*>(a1f + kb);
    short8 b0 = *reinterpret_cast<const short8*>(bp + kb);
    short8 b1 = *reinterpret_cast<const short8*>(bp + 16 * 1024 + kb);
    short8 b2 = *reinterpret_cast<const short8*>(bp + 32 * 1024 + kb);
    short8 b3 = *reinterpret_cast<const short8*>(bp + 48 * 1024 + kb);
    acc[0][0] = __builtin_amdgcn_mfma_f32_16x16x32_bf16(a0, b0, acc[0][0], 0, 0, 0);
    acc[0][1] = __builtin_amdgcn_mfma_f32_16x16x32_bf16(a0, b1, acc[0][1], 0, 0, 0);
    acc[0][2] = __builtin_amdgcn_mfma_f32_16x16x32_bf16(a0, b2, acc[0][2], 0, 0, 0);
    acc[0][3] = __builtin_amdgcn_mfma_f32_16x16x32_bf16(a0, b3, acc[0][3], 0, 0, 0);
    acc[1][0] = __builtin_amdgcn_mfma_f32_16x16x32_bf16(a1, b0, acc[1][0], 0, 0, 0);
    acc[1][1] = __builtin_amdgcn_mfma_f32_16x16x32_bf16(a1, b1, acc[1][1], 0, 0, 0);
    acc[1][2] = __builtin_amdgcn_mfma_f32_16x16x32_bf16(a1, b2, acc[1][2], 0, 0, 0);
    acc[1][3] = __builtin_amdgcn_mfma_f32_16x16x32_bf16(a1, b3, acc[1][3], 0, 0, 0);
  }

  // K phase 2: to_hidden path (feats · th_w^T), K=256 (Wcat cols 768..1023)
  const unsigned short* a0t = featsbf + (size_t)s_ent[lr] * 256 + kg * 8;
  const unsigned short* a1t = featsbf + (size_t)s_ent[16 + lr] * 256 + kg * 8;
  for (int kb = 0; kb < 256; kb += 32) {
    short8 a0 = *reinterpret_cast<const short8*>(a0t + kb);
    short8 a1 = *reinterpret_cast<const short8*>(a1t + kb);
    short8 b0 = *reinterpret_cast<const short8*>(bp + 768 + kb);
    short8 b1 = *reinterpret_cast<const short8*>(bp + 16 * 1024 + 768 + kb);
    short8 b2 = *reinterpret_cast<const short8*>(bp + 32 * 1024 + 768 + kb);
    short8 b3 = *reinterpret_cast<const short8*>(bp + 48 * 1024 + 768 + kb);
    acc[0][0] = __builtin_amdgcn_mfma_f32_16x16x32_bf16(a0, b0, acc[0][0], 0, 0, 0);
    acc[0][1] = __builtin_amdgcn_mfma_f32_16x16x32_bf16(a0, b1, acc[0][1], 0, 0, 0);
    acc[0][2] = __builtin_amdgcn_mfma_f32_16x16x32_bf16(a0, b2, acc[0][2], 0, 0, 0);
    acc[0][3] = __builtin_amdgcn_mfma_f32_16x16x32_bf16(a0, b3, acc[0][3], 0, 0, 0);
    acc[1][0] = __builtin_amdgcn_mfma_f32_16x16x32_bf16(a1, b0, acc[1][0], 0, 0, 0);
    acc[1][1] = __builtin_amdgcn_mfma_f32_16x16x32_bf16(a1, b1, acc[1][1], 0, 0, 0);
    acc[1][2] = __builtin_amdgcn_mfma_f32_16x16x32_bf16(a1, b2, acc[1][2], 0, 0, 0);
    acc[1][3] = __builtin_amdgcn_mfma_f32_16x16x32_bf16(a1, b3, acc[1][3], 0, 0, 0);
  }

  // epilogue: D col = lane&15 (out-dim), row = (lane>>4)*4 + reg (entry)
  #pragma unroll
  for (int j = 0; j < 4; ++j) {
    int d = n0 + j * 16 + lr;
    float bsum = th_b[e * 768 + d] + res_b[e * 768 + d];
    #pragma unroll
    for (int i = 0; i < 2; ++i) {
      #pragma unroll
      for (int r = 0; r < 4; ++r) {
        int m = i * 16 + kg * 4 + r;
        float v = s_g[m] * (acc[i][j][r] + bsum);
        atomicAdd(&moe[(size_t)s_tok[m] * 768 + d], v);
      }
    }
  }
}

// ---------------- final projection via MFMA + transpose write --------------
__global__ __launch_bounds__(256) void emb_mfma(const unsigned short* __restrict__ Mbuf, // [8192][768]
                                                const unsigned short* __restrict__ Wte,  // [256][768]
                                                const float* __restrict__ te_b,
                                                float* __restrict__ out)
{
  int tt = blockIdx.x;          // 32-token tile
  int tid = threadIdx.x;
  int wid = tid >> 6, lane = tid & 63;
  int lr = lane & 15, kg = lane >> 4;
  int t0 = tt * 32;
  int n0 = wid * 64;
  const unsigned short* a0p = Mbuf + (size_t)(t0 + lr) * 768 + kg * 8;
  const unsigned short* a1p = a0p + 16 * 768;
  const unsigned short* bp = Wte + (size_t)(n0 + lr) * 768 + kg * 8;

  f32x4 acc[2][4] = {};
  for (int kb = 0; kb < 768; kb += 32) {
    short8 a0 = *reinterpret_cast<const short8*>(a0p + kb);
    short8 a1 = *reinterpret_cast<const short8*>(a1p + kb);
    short8 b0 = *reinterpret_cast<const short8*>(bp + kb);
    short8 b1 = *reinterpret_cast<const short8*>(bp + 16 * 768 + kb);
    short8 b2 = *reinterpret_cast<const short8*>(bp + 32 * 768 + kb);
    short8 b3 = *reinterpret_cast<const short8*>(bp + 48 * 768 + kb);
    acc[0][0] = __builtin_amdgcn_mfma_f32_16x16x32_bf16(a0, b0, acc[0][0], 0, 0, 0);
    acc[0][1] = __builtin_amdgcn_mfma_f32_16x16x32_bf16(a0, b1, acc[0][1], 0, 0, 0);
    acc[0][2] = __builtin_amdgcn_mfma_f32_16x16x32_bf16(a0, b2, acc[0][2], 0, 0, 0);
    acc[0][3] = __builtin_amdgcn_mfma_f32_16x16x32_bf16(a0, b3, acc[0][3], 0, 0, 0);
    acc[1][0] = __builtin_amdgcn_mfma_f32_16x16x32_bf16(a1, b0, acc[1][0], 0, 0, 0);
    acc[1][1] = __builtin_amdgcn_mfma_f32_16x16x32_bf16(a1, b1, acc[1][1], 0, 0, 0);
    acc[1][2] = __builtin_amdgcn_mfma_f32_16x16x32_bf16(a1, b2, acc[1][2], 0, 0, 0);
    acc[1][3] = __builtin_amdgcn_mfma_f32_16x16x32_bf16(a1, b3, acc[1][3], 0, 0, 0);
  }

  #pragma unroll
  for (int j = 0; j < 4; ++j) {
    int d = n0 + j * 16 + lr;
    float b = te_b[d];
    #pragma unroll
    for (int i = 0; i < 2; ++i) {
      #pragma unroll
      for (int r = 0; r < 4; ++r) {
        int m = i * 16 + kg * 4 + r;
        int t = t0 + m;
        int bi = t >> 8, nn = t & 255;
        out[((size_t)bi * 256 + d) * 256 + nn] = acc[i][j][r] + b;
      }
    }
  }
}

extern "C" void kernel_launch(void* const* d_in, const int* in_sizes, int n_in,
                              void* d_out, int out_size, void* d_ws, size_t ws_size,
                              hipStream_t stream)
{
  (void)in_sizes; (void)n_in; (void)out_size; (void)ws_size;
  const float* x    = (const float*)d_in[0];
  const float* gw   = (const float*)d_in[1];
  const float* gb   = (const float*)d_in[2];
  const float* dw1w = (const float*)d_in[3];
  const float* dw1b = (const float*)d_in[4];
  const float* pw1w = (const float*)d_in[5];
  const float* pw1b = (const float*)d_in[6];
  const float* dw2w = (const float*)d_in[7];
  const float* dw2b = (const float*)d_in[8];
  const float* pw2w = (const float*)d_in[9];
  const float* pw2b = (const float*)d_in[10];
  const float* dw3w = (const float*)d_in[11];
  const float* dw3b = (const float*)d_in[12];
  const float* pw3w = (const float*)d_in[13];
  const float* pw3b = (const float*)d_in[14];
  const float* thw  = (const float*)d_in[15];
  const float* thb  = (const float*)d_in[16];
  const float* resw = (const float*)d_in[17];
  const float* resb = (const float*)d_in[18];
  const float* tew  = (const float*)d_in[19];
  const float* teb  = (const float*)d_in[20];

  float* ws    = (float*)d_ws;
  float* flat  = ws;                      // 6291456 f  (dead after f2bf(flat)+cnn; overlaid by Wcat/Wte)
  float* moe   = ws + 6291456;            // 6291456 f
  float* feats = ws + 12582912;           // 4194304 f  (dead after f2bf(feats); overlaid by Mbuf)
  float* gval  = ws + 16777216;           // 16384 f
  int*   gidx  = (int*)(ws + 16793600);   // 16384 i
  float* aux   = ws + 16809984;           // 256 f
  int*   cnt   = (int*)(ws + 16810240);   // 8 i
  int*   bin   = (int*)(ws + 16810248);   // 65536 i
  unsigned short* flatbf  = (unsigned short*)(ws + 16875784);  // 8192*768 bf16
  unsigned short* featsbf = (unsigned short*)(ws + 20021512);  // 16384*256 bf16
  unsigned short* Wcat    = (unsigned short*)(ws);             // 8*768*1024 bf16 (over flat)
  unsigned short* Wte     = (unsigned short*)(ws + 3145728);   // 256*768 bf16 (over flat)
  unsigned short* Mbuf    = (unsigned short*)(ws + 12582912);  // 8192*768 bf16 (over feats)
  float* out   = (float*)d_out;

  hipMemsetAsync(moe, 0, 6291456 * sizeof(float), stream);
  hipMemsetAsync(aux, 0, 264 * sizeof(float), stream);   // aux(256) + cnt(8)

  patch_kernel<<<8192, 256, 0, stream>>>(x, flat);
  gate_kernel<<<NTOK / GTOK, 256, 0, stream>>>(flat, gw, gb, gidx, gval, aux);
  bin_kernel<<<64, 256, 0, stream>>>(gidx, cnt, bin);
  laux_kernel<<<1, 64, 0, stream>>>(aux, out);
  cnn_kernel<<<16384, 256, 0, stream>>>(flat, gidx, dw1w, dw1b, pw1w, pw1b,
                                        dw2w, dw2b, pw2w, pw2b, dw3w, dw3b,
                                        pw3w, pw3b, feats);
  // bf16 conversions (flat/feats must precede Wcat overlay of flat region)
  f2bf_kernel<<<6144, 256, 0, stream>>>(flat, flatbf);    // 6291456
  f2bf_kernel<<<4096, 256, 0, stream>>>(feats, featsbf);  // 4194304
  wcat_kernel<<<6144, 256, 0, stream>>>(resw, thw, Wcat); // writes over flat (dead)
  f2bf_kernel<<<192, 256, 0, stream>>>(tew, Wte);         // 196608

  dim3 cg(256, 3, 8);
  combine_mfma<<<cg, 256, 0, stream>>>(flatbf, featsbf, Wcat, gval, bin, cnt,
                                       thb, resb, moe);
  f2bf_kernel<<<6144, 256, 0, stream>>>(moe, Mbuf);       // over feats (dead)
  emb_mfma<<<256, 256, 0, stream>>>(Mbuf, Wte, teb, out);
}

// Round 4
// 460.240 us; speedup vs baseline: 5.7621x; 1.9989x over previous
//
#include <hip/hip_runtime.h>

#define NTOK 8192
#define GTOK 32   // tokens per gate block

typedef __attribute__((ext_vector_type(8))) short short8;
typedef __attribute__((ext_vector_type(4))) float f32x4;

__device__ __forceinline__ unsigned short f2bf(float f) {
  unsigned u = __float_as_uint(f);
  u += 0x7FFFu + ((u >> 16) & 1u);
  return (unsigned short)(u >> 16);
}
__device__ __forceinline__ float bf2f(unsigned short u) {
  return __uint_as_float(((unsigned)u) << 16);
}

// ---------------- patchify: x[B,3,256,256] -> flat[T,768] (C,P,P-major) -----
__global__ __launch_bounds__(256) void patch_kernel(const float* __restrict__ x,
                                                    float* __restrict__ flat)
{
  int t = blockIdx.x;          // 0..8191
  int tid = threadIdx.x;
  int b = t >> 8, ph = (t >> 4) & 15, pw = t & 15;
  const float* xb = x + (size_t)b * 3 * 256 * 256;
  #pragma unroll
  for (int r = 0; r < 3; ++r) {
    int d = r * 256 + tid;
    int c = d >> 8, i = (d >> 4) & 15, j = d & 15;
    flat[(size_t)t * 768 + d] = xb[((size_t)c * 256 + ph * 16 + i) * 256 + pw * 16 + j];
  }
}

// ---------------- gate (fp32 flat; LDS-reduced aux) ------------------------
__global__ __launch_bounds__(256) void gate_kernel(const float* __restrict__ flat,
                                                   const float* __restrict__ gw,
                                                   const float* __restrict__ gb,
                                                   int* __restrict__ gidx,
                                                   float* __restrict__ gval,
                                                   float* __restrict__ aux)
{
  __shared__ float s_red[16];   // [0..7] ce partial, [8..15] me partial
  int tid = threadIdx.x;
  if (tid < 16) s_red[tid] = 0.f;
  __syncthreads();
  int wid = tid >> 6, lane = tid & 63;

  for (int it = 0; it < GTOK / 4; ++it) {
    int t = blockIdx.x * GTOK + it * 4 + wid;
    float acc[8];
    #pragma unroll
    for (int e = 0; e < 8; ++e) acc[e] = 0.f;
    const float* fr = flat + (size_t)t * 768;
    for (int k = lane; k < 768; k += 64) {
      float v = fr[k];
      const float* g = gw + k * 8;
      #pragma unroll
      for (int e = 0; e < 8; ++e) acc[e] += v * g[e];
    }
    #pragma unroll
    for (int e = 0; e < 8; ++e) {
      #pragma unroll
      for (int off = 32; off > 0; off >>= 1)
        acc[e] += __shfl_down(acc[e], off, 64);
    }
    if (lane == 0) {
      float lg[8];
      #pragma unroll
      for (int e = 0; e < 8; ++e) lg[e] = acc[e] + gb[e];
      int i0 = 0; float v0 = lg[0];
      #pragma unroll
      for (int e = 1; e < 8; ++e) if (lg[e] > v0) { v0 = lg[e]; i0 = e; }
      int i1 = -1; float v1 = -1e30f;
      #pragma unroll
      for (int e = 0; e < 8; ++e) { if (e == i0) continue; if (lg[e] > v1) { v1 = lg[e]; i1 = e; } }
      float e1 = __expf(v1 - v0);
      float s0 = 1.f / (1.f + e1);
      float s1 = e1 * s0;
      gidx[t * 2] = i0; gidx[t * 2 + 1] = i1;
      gval[t * 2] = s0; gval[t * 2 + 1] = s1;
      float sum = 0.f, p[8];
      #pragma unroll
      for (int e = 0; e < 8; ++e) { p[e] = __expf(lg[e] - v0); sum += p[e]; }
      float inv = 1.f / sum;
      #pragma unroll
      for (int e = 0; e < 8; ++e) atomicAdd(&s_red[8 + e], p[e] * inv);
      atomicAdd(&s_red[i0], 1.f);
    }
  }
  __syncthreads();
  if (tid < 8) {
    atomicAdd(&aux[tid * 16], s_red[tid]);           // ce
    atomicAdd(&aux[128 + tid * 16], s_red[8 + tid]); // me
  }
}

// ---------------- bin token-slots by expert --------------------------------
__global__ __launch_bounds__(256) void bin_kernel(const int* __restrict__ gidx,
                                                  int* __restrict__ cnt,
                                                  int* __restrict__ bin)
{
  int idx = blockIdx.x * 256 + threadIdx.x;   // 0..16383 (t*2+slot)
  int e = gidx[idx];
  int pos = atomicAdd(&cnt[e], 1);
  bin[e * 8192 + pos] = idx;
}

// ---------------- l_aux finalize -------------------------------------------
__global__ void laux_kernel(const float* __restrict__ aux, float* __restrict__ out)
{
  if (threadIdx.x == 0 && blockIdx.x == 0) {
    float l = 0.f;
    for (int e = 0; e < 8; ++e)
      l += (aux[e * 16] / 8192.f) * (aux[128 + e * 16] / 8192.f);
    out[2097152] = 8.f * l;
  }
}

// ---------------- fp32 -> bf16 bulk convert (n multiple of 1024) -----------
__global__ __launch_bounds__(256) void f2bf_kernel(const float* __restrict__ in,
                                                   unsigned short* __restrict__ out)
{
  size_t i = (size_t)blockIdx.x * 1024 + threadIdx.x * 4;
  float4 v = *reinterpret_cast<const float4*>(in + i);
  ushort4 o;
  o.x = f2bf(v.x); o.y = f2bf(v.y); o.z = f2bf(v.z); o.w = f2bf(v.w);
  *reinterpret_cast<ushort4*>(out + i) = o;
}

// ---------------- Wcat[e][o][1024] = res_w[e][o][0:768] || th_w[e][o][0:256]
__global__ __launch_bounds__(256) void wcat_kernel(const float* __restrict__ resw,
                                                   const float* __restrict__ thw,
                                                   unsigned short* __restrict__ Wcat)
{
  int row = blockIdx.x;               // 0..6143 == e*768+o
  int k = threadIdx.x * 4;            // 0..1023
  float4 v;
  if (k < 768) v = *reinterpret_cast<const float4*>(resw + (size_t)row * 768 + k);
  else         v = *reinterpret_cast<const float4*>(thw + (size_t)row * 256 + (k - 768));
  ushort4 o;
  o.x = f2bf(v.x); o.y = f2bf(v.y); o.z = f2bf(v.z); o.w = f2bf(v.w);
  *reinterpret_cast<ushort4*>(Wcat + (size_t)row * 1024 + k) = o;
}

// ---------------- expert CNN tower via MFMA: 4 entries of one expert/block -
__global__ __launch_bounds__(256) void cnn_mfma(
    const unsigned short* __restrict__ flatbf, const int* __restrict__ bin,
    const int* __restrict__ cnt,
    const float* __restrict__ dw1w, const float* __restrict__ dw1b,
    const float* __restrict__ pw1w, const float* __restrict__ pw1b,
    const float* __restrict__ dw2w, const float* __restrict__ dw2b,
    const unsigned short* __restrict__ w2bf, const float* __restrict__ pw2b,
    const float* __restrict__ dw3w, const float* __restrict__ dw3b,
    const unsigned short* __restrict__ w3bf, const float* __restrict__ pw3b,
    unsigned short* __restrict__ featsbf)
{
  int e = blockIdx.y;
  int n = cnt[e];
  int chunk = blockIdx.x;
  if (chunk * 4 >= n) return;

  __shared__ unsigned short s_in[4 * 768];   // dw1 input, bf16 [en][3][16][16]
  __shared__ float          s_a[4 * 192];    // dw1 out fp32 [en][3][8][8]
  __shared__ unsigned short s_c[64 * 64];    // dw2 out bf16 [row=en*16+pos][64ch] XOR-swz
  __shared__ unsigned short s_d[4 * 128 * 16]; // pw2 out bf16 [en][128ch][16pos]
  __shared__ unsigned short s_e3[16 * 128];  // dw3 out bf16 [row=en*4+q][128ch] XOR-swz
  __shared__ int s_ent[4];
  __shared__ int s_val[4];

  int tid = threadIdx.x;
  if (tid < 4) {
    int idx = chunk * 4 + tid;
    int ok = idx < n;
    s_ent[tid] = bin[e * 8192 + (ok ? idx : 0)];
    s_val[tid] = ok;
  }
  __syncthreads();

  // ---- load 4x768 bf16 rows into LDS (12 bf16/thread) ----
  {
    int en = tid >> 6, li = tid & 63;
    int tok = s_ent[en] >> 1;
    const unsigned short* src = flatbf + (size_t)tok * 768 + li * 12;
    unsigned short* dst = s_in + en * 768 + li * 12;
    #pragma unroll
    for (int r = 0; r < 3; ++r)
      *reinterpret_cast<ushort4*>(dst + r * 4) = *reinterpret_cast<const ushort4*>(src + r * 4);
  }
  __syncthreads();

  // ---- dw1: depthwise 3x3 s2 p1, 16->8, C=3 (768 outputs) ----
  #pragma unroll
  for (int r = 0; r < 3; ++r) {
    int idx = r * 256 + tid;             // 0..767
    int en = idx / 192, rem = idx % 192;
    int c = rem >> 6, p = rem & 63, oy = p >> 3, ox = p & 7;
    const float* w = dw1w + (e * 3 + c) * 9;
    float acc = dw1b[e * 3 + c];
    #pragma unroll
    for (int ky = 0; ky < 3; ++ky) {
      int iy = oy * 2 - 1 + ky; if ((unsigned)iy > 15u) continue;
      #pragma unroll
      for (int kx = 0; kx < 3; ++kx) {
        int ix = ox * 2 - 1 + kx; if ((unsigned)ix > 15u) continue;
        acc += w[ky * 3 + kx] * bf2f(s_in[en * 768 + c * 256 + iy * 16 + ix]);
      }
    }
    s_a[en * 192 + rem] = fmaxf(acc, 0.f);
  }
  __syncthreads();

  // ---- pw1 (3->64) + dw2 (8->4) fused in registers; thread=(entry,ch) ----
  {
    int en = tid >> 6, ch = tid & 63;
    const float* w1 = pw1w + (e * 64 + ch) * 3;
    float w10 = w1[0], w11 = w1[1], w12 = w1[2];
    float b1 = pw1b[e * 64 + ch];
    float v[64];
    const float* sa = s_a + en * 192;
    #pragma unroll
    for (int p = 0; p < 64; p += 4) {
      float4 a0 = *reinterpret_cast<const float4*>(sa + p);
      float4 a1 = *reinterpret_cast<const float4*>(sa + 64 + p);
      float4 a2 = *reinterpret_cast<const float4*>(sa + 128 + p);
      v[p + 0] = fmaxf(b1 + w10 * a0.x + w11 * a1.x + w12 * a2.x, 0.f);
      v[p + 1] = fmaxf(b1 + w10 * a0.y + w11 * a1.y + w12 * a2.y, 0.f);
      v[p + 2] = fmaxf(b1 + w10 * a0.z + w11 * a1.z + w12 * a2.z, 0.f);
      v[p + 3] = fmaxf(b1 + w10 * a0.w + w11 * a1.w + w12 * a2.w, 0.f);
    }
    const float* w2d = dw2w + (e * 64 + ch) * 9;
    float b2 = dw2b[e * 64 + ch];
    #pragma unroll
    for (int oy = 0; oy < 4; ++oy) {
      #pragma unroll
      for (int ox = 0; ox < 4; ++ox) {
        float acc = b2;
        #pragma unroll
        for (int ky = 0; ky < 3; ++ky) {
          int iy = oy * 2 - 1 + ky; if ((unsigned)iy > 7u) continue;
          #pragma unroll
          for (int kx = 0; kx < 3; ++kx) {
            int ix = ox * 2 - 1 + kx; if ((unsigned)ix > 7u) continue;
            acc += w2d[ky * 3 + kx] * v[iy * 8 + ix];
          }
        }
        int row = en * 16 + oy * 4 + ox;
        int elem = ch ^ ((row & 7) << 3);
        s_c[row * 64 + elem] = f2bf(fmaxf(acc, 0.f));
      }
    }
  }
  __syncthreads();

  // ---- pw2 via MFMA: M=128(o), N=64(pos), K=64 ----
  {
    int wid = tid >> 6, lane = tid & 63, lr = lane & 15, kg = lane >> 4;
    f32x4 acc[2][4] = {};
    #pragma unroll
    for (int ks = 0; ks < 2; ++ks) {
      short8 a[2], b[4];
      #pragma unroll
      for (int m = 0; m < 2; ++m) {
        int o = (wid * 2 + m) * 16 + lr;
        a[m] = *reinterpret_cast<const short8*>(w2bf + ((size_t)e * 128 + o) * 64 + ks * 32 + kg * 8);
      }
      #pragma unroll
      for (int nt = 0; nt < 4; ++nt) {
        int row = nt * 16 + lr;
        int k0 = (ks * 32 + kg * 8) ^ ((row & 7) << 3);
        b[nt] = *reinterpret_cast<const short8*>(s_c + row * 64 + k0);
      }
      #pragma unroll
      for (int m = 0; m < 2; ++m)
        #pragma unroll
        for (int nt = 0; nt < 4; ++nt)
          acc[m][nt] = __builtin_amdgcn_mfma_f32_16x16x32_bf16(a[m], b[nt], acc[m][nt], 0, 0, 0);
    }
    // epilogue: o = mt*16+kg*4+r, pos(col) = lr; entry = nt
    #pragma unroll
    for (int m = 0; m < 2; ++m) {
      #pragma unroll
      for (int r = 0; r < 4; ++r) {
        int o = (wid * 2 + m) * 16 + kg * 4 + r;
        float bb = pw2b[e * 128 + o];
        #pragma unroll
        for (int nt = 0; nt < 4; ++nt)
          s_d[(nt * 128 + o) * 16 + lr] = f2bf(fmaxf(acc[m][nt][r] + bb, 0.f));
      }
    }
  }
  __syncthreads();

  // ---- dw3: depthwise 3x3 s2 p1, 4->2, C=128 (512 rows, 2/thread) ----
  #pragma unroll
  for (int r2 = 0; r2 < 2; ++r2) {
    int idx = r2 * 256 + tid;            // 0..511
    int en = idx >> 7, ch = idx & 127;
    const unsigned short* sd = s_d + (en * 128 + ch) * 16;
    float in[16];
    #pragma unroll
    for (int q = 0; q < 16; ++q) in[q] = bf2f(sd[q]);
    const float* wd = dw3w + (e * 128 + ch) * 9;
    float b3 = dw3b[e * 128 + ch];
    #pragma unroll
    for (int oy = 0; oy < 2; ++oy) {
      #pragma unroll
      for (int ox = 0; ox < 2; ++ox) {
        float acc = b3;
        #pragma unroll
        for (int ky = 0; ky < 3; ++ky) {
          int iy = oy * 2 - 1 + ky; if ((unsigned)iy > 3u) continue;
          #pragma unroll
          for (int kx = 0; kx < 3; ++kx) {
            int ix = ox * 2 - 1 + kx; if ((unsigned)ix > 3u) continue;
            acc += wd[ky * 3 + kx] * in[iy * 4 + ix];
          }
        }
        int row = en * 4 + oy * 2 + ox;
        int elem = ch ^ ((row & 7) << 3);
        s_e3[row * 128 + elem] = f2bf(fmaxf(acc, 0.f));
      }
    }
  }
  __syncthreads();

  // ---- pw3 via MFMA: M=256(o), N=16(pos=en*4+q), K=128; relu+meanpool ----
  {
    int wid = tid >> 6, lane = tid & 63, lr = lane & 15, kg = lane >> 4;
    f32x4 acc3[4] = {};
    #pragma unroll
    for (int ks = 0; ks < 4; ++ks) {
      int k0 = (ks * 32 + kg * 8) ^ ((lr & 7) << 3);
      short8 b = *reinterpret_cast<const short8*>(s_e3 + lr * 128 + k0);
      #pragma unroll
      for (int m = 0; m < 4; ++m) {
        int o = (wid * 4 + m) * 16 + lr;
        short8 a = *reinterpret_cast<const short8*>(w3bf + ((size_t)e * 256 + o) * 128 + ks * 32 + kg * 8);
        acc3[m] = __builtin_amdgcn_mfma_f32_16x16x32_bf16(a, b, acc3[m], 0, 0, 0);
      }
    }
    int enL = lr >> 2;
    int ent = s_ent[enL];
    int ok = s_val[enL] && ((lr & 3) == 0);
    #pragma unroll
    for (int m = 0; m < 4; ++m) {
      #pragma unroll
      for (int r = 0; r < 4; ++r) {
        int o = (wid * 4 + m) * 16 + kg * 4 + r;
        float val = fmaxf(acc3[m][r] + pw3b[e * 256 + o], 0.f);
        val += __shfl_xor(val, 1, 64);
        val += __shfl_xor(val, 2, 64);
        if (ok) featsbf[(size_t)ent * 256 + o] = f2bf(val * 0.25f);
      }
    }
  }
}

// ---------------- grouped combine GEMM via MFMA ----------------------------
__global__ __launch_bounds__(256) void combine_mfma(
    const unsigned short* __restrict__ flatbf,   // [8192][768]
    const unsigned short* __restrict__ featsbf,  // [16384][256]
    const unsigned short* __restrict__ Wcat,     // [8][768][1024]
    const float* __restrict__ gval, const int* __restrict__ bin,
    const int* __restrict__ cnt, const float* __restrict__ th_b,
    const float* __restrict__ res_b, float* __restrict__ moe)
{
  int e = blockIdx.z;
  int n = cnt[e];
  int chunk = blockIdx.x;
  if (chunk * 32 >= n) return;
  int dt = blockIdx.y;          // 0..2
  int tid = threadIdx.x;
  int wid = tid >> 6, lane = tid & 63;
  __shared__ int s_ent[32];
  __shared__ int s_tok[32];
  __shared__ float s_g[32];
  if (tid < 32) {
    int idx = chunk * 32 + tid;
    if (idx < n) {
      int ent = bin[e * 8192 + idx];
      s_ent[tid] = ent; s_tok[tid] = ent >> 1; s_g[tid] = gval[ent];
    } else {
      int ent0 = bin[e * 8192];
      s_ent[tid] = ent0; s_tok[tid] = ent0 >> 1; s_g[tid] = 0.f;
    }
  }
  __syncthreads();

  int lr = lane & 15, kg = lane >> 4;   // row/col-in-tile, k-group
  int n0 = dt * 256 + wid * 64;
  const unsigned short* a0f = flatbf + (size_t)s_tok[lr] * 768 + kg * 8;
  const unsigned short* a1f = flatbf + (size_t)s_tok[16 + lr] * 768 + kg * 8;
  const unsigned short* bp = Wcat + ((size_t)e * 768 + n0 + lr) * 1024 + kg * 8;

  f32x4 acc[2][4] = {};

  for (int kb = 0; kb < 768; kb += 32) {
    short8 a0 = *reinterpret_cast<const short8*>(a0f + kb);
    short8 a1 = *reinterpret_cast<const short8*>(a1f + kb);
    short8 b0 = *reinterpret_cast<const short8*>(bp + kb);
    short8 b1 = *reinterpret_cast<const short8*>(bp + 16 * 1024 + kb);
    short8 b2 = *reinterpret_cast<const short8*>(bp + 32 * 1024 + kb);
    short8 b3 = *reinterpret_cast<const short8*>(bp + 48 * 1024 + kb);
    acc[0][0] = __builtin_amdgcn_mfma_f32_16x16x32_bf16(a0, b0, acc[0][0], 0, 0, 0);
    acc[0][1] = __builtin_amdgcn_mfma_f32_16x16x32_bf16(a0, b1, acc[0][1], 0, 0, 0);
    acc[0][2] = __builtin_amdgcn_mfma_f32_16x16x32_bf16(a0, b2, acc[0][2], 0, 0, 0);
    acc[0][3] = __builtin_amdgcn_mfma_f32_16x16x32_bf16(a0, b3, acc[0][3], 0, 0, 0);
    acc[1][0] = __builtin_amdgcn_mfma_f32_16x16x32_bf16(a1, b0, acc[1][0], 0, 0, 0);
    acc[1][1] = __builtin_amdgcn_mfma_f32_16x16x32_bf16(a1, b1, acc[1][1], 0, 0, 0);
    acc[1][2] = __builtin_amdgcn_mfma_f32_16x16x32_bf16(a1, b2, acc[1][2], 0, 0, 0);
    acc[1][3] = __builtin_amdgcn_mfma_f32_16x16x32_bf16(a1, b3, acc[1][3], 0, 0, 0);
  }

  const unsigned short* a0t = featsbf + (size_t)s_ent[lr] * 256 + kg * 8;
  const unsigned short* a1t = featsbf + (size_t)s_ent[16 + lr] * 256 + kg * 8;
  for (int kb = 0; kb < 256; kb += 32) {
    short8 a0 = *reinterpret_cast<const short8*>(a0t + kb);
    short8 a1 = *reinterpret_cast<const short8*>(a1t + kb);
    short8 b0 = *reinterpret_cast<const short8*>(bp + 768 + kb);
    short8 b1 = *reinterpret_cast<const short8*>(bp + 16 * 1024 + 768 + kb);
    short8 b2 = *reinterpret_cast<const short8*>(bp + 32 * 1024 + 768 + kb);
    short8 b3 = *reinterpret_cast<const short8*>(bp + 48 * 1024 + 768 + kb);
    acc[0][0] = __builtin_amdgcn_mfma_f32_16x16x32_bf16(a0, b0, acc[0][0], 0, 0, 0);
    acc[0][1] = __builtin_amdgcn_mfma_f32_16x16x32_bf16(a0, b1, acc[0][1], 0, 0, 0);
    acc[0][2] = __builtin_amdgcn_mfma_f32_16x16x32_bf16(a0, b2, acc[0][2], 0, 0, 0);
    acc[0][3] = __builtin_amdgcn_mfma_f32_16x16x32_bf16(a0, b3, acc[0][3], 0, 0, 0);
    acc[1][0] = __builtin_amdgcn_mfma_f32_16x16x32_bf16(a1, b0, acc[1][0], 0, 0, 0);
    acc[1][1] = __builtin_amdgcn_mfma_f32_16x16x32_bf16(a1, b1, acc[1][1], 0, 0, 0);
    acc[1][2] = __builtin_amdgcn_mfma_f32_16x16x32_bf16(a1, b2, acc[1][2], 0, 0, 0);
    acc[1][3] = __builtin_amdgcn_mfma_f32_16x16x32_bf16(a1, b3, acc[1][3], 0, 0, 0);
  }

  #pragma unroll
  for (int j = 0; j < 4; ++j) {
    int d = n0 + j * 16 + lr;
    float bsum = th_b[e * 768 + d] + res_b[e * 768 + d];
    #pragma unroll
    for (int i = 0; i < 2; ++i) {
      #pragma unroll
      for (int r = 0; r < 4; ++r) {
        int m = i * 16 + kg * 4 + r;
        float v = s_g[m] * (acc[i][j][r] + bsum);
        atomicAdd(&moe[(size_t)s_tok[m] * 768 + d], v);
      }
    }
  }
}

// ---------------- final projection via MFMA + transpose write --------------
__global__ __launch_bounds__(256) void emb_mfma(const unsigned short* __restrict__ Mbuf, // [8192][768]
                                                const unsigned short* __restrict__ Wte,  // [256][768]
                                                const float* __restrict__ te_b,
                                                float* __restrict__ out)
{
  int tt = blockIdx.x;          // 32-token tile
  int tid = threadIdx.x;
  int wid = tid >> 6, lane = tid & 63;
  int lr = lane & 15, kg = lane >> 4;
  int t0 = tt * 32;
  int n0 = wid * 64;
  const unsigned short* a0p = Mbuf + (size_t)(t0 + lr) * 768 + kg * 8;
  const unsigned short* a1p = a0p + 16 * 768;
  const unsigned short* bp = Wte + (size_t)(n0 + lr) * 768 + kg * 8;

  f32x4 acc[2][4] = {};
  for (int kb = 0; kb < 768; kb += 32) {
    short8 a0 = *reinterpret_cast<const short8*>(a0p + kb);
    short8 a1 = *reinterpret_cast<const short8*>(a1p + kb);
    short8 b0 = *reinterpret_cast<const short8*>(bp + kb);
    short8 b1 = *reinterpret_cast<const short8*>(bp + 16 * 768 + kb);
    short8 b2 = *reinterpret_cast<const short8*>(bp + 32 * 768 + kb);
    short8 b3 = *reinterpret_cast<const short8*>(bp + 48 * 768 + kb);
    acc[0][0] = __builtin_amdgcn_mfma_f32_16x16x32_bf16(a0, b0, acc[0][0], 0, 0, 0);
    acc[0][1] = __builtin_amdgcn_mfma_f32_16x16x32_bf16(a0, b1, acc[0][1], 0, 0, 0);
    acc[0][2] = __builtin_amdgcn_mfma_f32_16x16x32_bf16(a0, b2, acc[0][2], 0, 0, 0);
    acc[0][3] = __builtin_amdgcn_mfma_f32_16x16x32_bf16(a0, b3, acc[0][3], 0, 0, 0);
    acc[1][0] = __builtin_amdgcn_mfma_f32_16x16x32_bf16(a1, b0, acc[1][0], 0, 0, 0);
    acc[1][1] = __builtin_amdgcn_mfma_f32_16x16x32_bf16(a1, b1, acc[1][1], 0, 0, 0);
    acc[1][2] = __builtin_amdgcn_mfma_f32_16x16x32_bf16(a1, b2, acc[1][2], 0, 0, 0);
    acc[1][3] = __builtin_amdgcn_mfma_f32_16x16x32_bf16(a1, b3, acc[1][3], 0, 0, 0);
  }

  #pragma unroll
  for (int j = 0; j < 4; ++j) {
    int d = n0 + j * 16 + lr;
    float b = te_b[d];
    #pragma unroll
    for (int i = 0; i < 2; ++i) {
      #pragma unroll
      for (int r = 0; r < 4; ++r) {
        int m = i * 16 + kg * 4 + r;
        int t = t0 + m;
        int bi = t >> 8, nn = t & 255;
        out[((size_t)bi * 256 + d) * 256 + nn] = acc[i][j][r] + b;
      }
    }
  }
}

extern "C" void kernel_launch(void* const* d_in, const int* in_sizes, int n_in,
                              void* d_out, int out_size, void* d_ws, size_t ws_size,
                              hipStream_t stream)
{
  (void)in_sizes; (void)n_in; (void)out_size; (void)ws_size;
  const float* x    = (const float*)d_in[0];
  const float* gw   = (const float*)d_in[1];
  const float* gb   = (const float*)d_in[2];
  const float* dw1w = (const float*)d_in[3];
  const float* dw1b = (const float*)d_in[4];
  const float* pw1w = (const float*)d_in[5];
  const float* pw1b = (const float*)d_in[6];
  const float* dw2w = (const float*)d_in[7];
  const float* dw2b = (const float*)d_in[8];
  const float* pw2w = (const float*)d_in[9];
  const float* pw2b = (const float*)d_in[10];
  const float* dw3w = (const float*)d_in[11];
  const float* dw3b = (const float*)d_in[12];
  const float* pw3w = (const float*)d_in[13];
  const float* pw3b = (const float*)d_in[14];
  const float* thw  = (const float*)d_in[15];
  const float* thb  = (const float*)d_in[16];
  const float* resw = (const float*)d_in[17];
  const float* resb = (const float*)d_in[18];
  const float* tew  = (const float*)d_in[19];
  const float* teb  = (const float*)d_in[20];

  float* ws    = (float*)d_ws;
  float* flat  = ws;                      // 6291456 f (dead after gate+f2bf; overlaid by Wcat/Wte)
  float* moe   = ws + 6291456;            // 6291456 f
  // region 12582912..15728640: w2bf/w3bf during cnn, then Mbuf after combine
  unsigned short* w2bf = (unsigned short*)(ws + 12582912);  // 65536 bf16
  unsigned short* w3bf = (unsigned short*)(ws + 12615680);  // 262144 bf16
  unsigned short* Mbuf = (unsigned short*)(ws + 12582912);  // 8192*768 bf16
  float* gval  = ws + 16777216;           // 16384 f
  int*   gidx  = (int*)(ws + 16793600);   // 16384 i
  float* aux   = ws + 16809984;           // 256 f
  int*   cnt   = (int*)(ws + 16810240);   // 8 i
  int*   bin   = (int*)(ws + 16810248);   // 65536 i
  unsigned short* flatbf  = (unsigned short*)(ws + 16875784);  // 8192*768 bf16
  unsigned short* featsbf = (unsigned short*)(ws + 20021512);  // 16384*256 bf16
  unsigned short* Wcat    = (unsigned short*)(ws);             // 8*768*1024 bf16 (over flat)
  unsigned short* Wte     = (unsigned short*)(ws + 3145728);   // 256*768 bf16 (over flat)
  float* out   = (float*)d_out;

  hipMemsetAsync(moe, 0, 6291456 * sizeof(float), stream);
  hipMemsetAsync(aux, 0, 264 * sizeof(float), stream);   // aux(256) + cnt(8)

  patch_kernel<<<8192, 256, 0, stream>>>(x, flat);
  gate_kernel<<<NTOK / GTOK, 256, 0, stream>>>(flat, gw, gb, gidx, gval, aux);
  f2bf_kernel<<<6144, 256, 0, stream>>>(flat, flatbf);    // flat -> bf16
  bin_kernel<<<64, 256, 0, stream>>>(gidx, cnt, bin);
  laux_kernel<<<1, 64, 0, stream>>>(aux, out);
  f2bf_kernel<<<64, 256, 0, stream>>>(pw2w, w2bf);        // 65536
  f2bf_kernel<<<256, 256, 0, stream>>>(pw3w, w3bf);       // 262144

  dim3 cnng(2048, 8);
  cnn_mfma<<<cnng, 256, 0, stream>>>(flatbf, bin, cnt, dw1w, dw1b, pw1w, pw1b,
                                     dw2w, dw2b, w2bf, pw2b, dw3w, dw3b,
                                     w3bf, pw3b, featsbf);

  wcat_kernel<<<6144, 256, 0, stream>>>(resw, thw, Wcat); // over flat (dead)
  f2bf_kernel<<<192, 256, 0, stream>>>(tew, Wte);         // 196608

  dim3 cg(256, 3, 8);
  combine_mfma<<<cg, 256, 0, stream>>>(flatbf, featsbf, Wcat, gval, bin, cnt,
                                       thb, resb, moe);
  f2bf_kernel<<<6144, 256, 0, stream>>>(moe, Mbuf);       // over w2bf/w3bf (dead)
  emb_mfma<<<256, 256, 0, stream>>>(Mbuf, Wte, teb, out);
}